// Round 9
// baseline (445.422 us; speedup 1.0000x reference)
//
#include <hip/hip_runtime.h>
#include <math.h>

#define POSD 16
#define DEG_CAP 64    // fixed CSR row stride; P(indeg >= 64) ~ 1e-20 for Poisson(16)
#define NSLICE 16     // BN-stat atomic slices (390 serialized adds/addr - R13-safe)
#define KNODES 2      // nodes per wave in aggregate

typedef __attribute__((ext_vector_type(8))) __bf16 bf16x8;
typedef __attribute__((ext_vector_type(4))) float f32x4;

__device__ __forceinline__ unsigned short f2bf(float f){
  unsigned int u = __float_as_uint(f);
  u += 0x7FFF + ((u >> 16) & 1);          // round-to-nearest-even
  return (unsigned short)(u >> 16);
}
__device__ __forceinline__ float bf2f(unsigned short u){
  return __uint_as_float(((unsigned int)u) << 16);
}

// ---- init: starts + zero | x->bf16 | packs | uvw (scatter moved to GEMM1) ---
__global__ __launch_bounds__(256) void k_init(
    const int* __restrict__ batch, int* __restrict__ starts,
    float* __restrict__ bnP, float* __restrict__ pooled,
    const float* __restrict__ x, unsigned short* __restrict__ xb,
    const float* __restrict__ W_pos, const float* __restrict__ b_pos,
    const float* __restrict__ W1, const float* __restrict__ W2,
    unsigned short* __restrict__ W1t, unsigned short* __restrict__ W2t,
    float* __restrict__ uvw,
    int N, int nfb0, int nxb){
  int bx = blockIdx.x;
  int t = threadIdx.x;
  if (bx < nfb0){
    // starts + zero bnP/pooled
    int i = bx * 256 + t;
    if (i < 2 * NSLICE * 512) bnP[i] = 0.f;
    if (i < 64 * 256) pooled[i] = 0.f;
    if (i < N){
      int bi = batch[i];
      int bp = (i == 0) ? -1 : batch[i - 1];
      for (int b = bp + 1; b <= bi; ++b) starts[b] = i;
      if (i == N - 1){
        for (int b = bi + 1; b <= 64; ++b) starts[b] = N;
      }
    }
  } else if (bx < nfb0 + nxb){
    // x (fp32 [N,128]) -> xb (bf16 [N,128]); 8 elems per thread
    size_t idx8 = (size_t)(bx - nfb0) * 256 + t;     // unit = 8 floats
    if (idx8 * 8 < (size_t)N * 128){
      const float4* xs = (const float4*)(x + idx8 * 8);
      float4 v0 = xs[0], v1 = xs[1];
      ushort4 o0, o1;
      o0.x = f2bf(v0.x); o0.y = f2bf(v0.y); o0.z = f2bf(v0.z); o0.w = f2bf(v0.w);
      o1.x = f2bf(v1.x); o1.y = f2bf(v1.y); o1.z = f2bf(v1.z); o1.w = f2bf(v1.w);
      ushort4* od = (ushort4*)(xb + idx8 * 8);
      od[0] = o0; od[1] = o1;
    }
  } else if (bx < nfb0 + nxb + 128){
    // pack W1t [256 x 128] bf16 from W1 rows 0..127 (transposed)
    int idx = (bx - nfb0 - nxb) * 256 + t;
    int n = idx >> 7, k = idx & 127;
    W1t[idx] = f2bf(W1[(size_t)k * 256 + n]);
  } else if (bx < nfb0 + nxb + 128 + 256){
    // pack W2t [256 x 256] bf16 (transposed)
    int j = (bx - nfb0 - nxb - 128) * 256 + t;
    int n = j >> 8, k = j & 255;
    W2t[j] = f2bf(W2[(size_t)k * 256 + n]);
  } else {
    // uvw: rank-2 positional projection vectors (fp32, exact)
    float u = 0.f, v = 0.f, wv = 0.f;
    #pragma unroll
    for (int k = 0; k < POSD; ++k){
      float wc = W1[(size_t)(128 + k) * 256 + t];
      u  += W_pos[k] * wc;          // W_pos row 0
      v  += W_pos[POSD + k] * wc;   // W_pos row 1
      wv += b_pos[k] * wc;
    }
    uvw[t] = u; uvw[256 + t] = v; uvw[512 + t] = wv;
  }
}

// ---- bf16 MFMA GEMM + fused attention logits + co-scheduled CSR scatter -----
// Blocks [0,nsb): CSR scatter (latency-bound, no dependency on GEMM inputs;
// consumed only by the NEXT dispatch). Blocks [nsb,..): GEMM. The scatter's
// ~55us memory latency hides the GEMM's ~18us of MFMA work in one dispatch.
// POSC: add rank-2 positional correction rn*u + cn*v + w in the epilogue.
#define LDST 40   // LDS row stride in bf16 (2-way bank aliasing, free)
template<int POSC>
__global__ __launch_bounds__(256) void k_mfma_gemm(
    const unsigned short* __restrict__ A, const unsigned short* __restrict__ Bt,
    unsigned short* __restrict__ C,
    const float* __restrict__ a_src, const float* __restrict__ a_dst,
    float* __restrict__ alpS, float* __restrict__ alpD, int M, int Kp,
    const float* __restrict__ uvw, const int* __restrict__ batch,
    const int* __restrict__ starts,
    int nsb, const int* __restrict__ src, const int* __restrict__ dst,
    int* __restrict__ cnt, int* __restrict__ csr_src, int E){
  __shared__ unsigned short As[128 * LDST];
  __shared__ unsigned short Bs[128 * LDST];
  int bx = blockIdx.x;
  if (bx < nsb){
    int i = bx * 256 + threadIdx.x;
    if (i < E){
      int d = dst[i];
      int slot = atomicAdd(&cnt[d], 1);
      csr_src[(size_t)d * DEG_CAP + slot] = src[i];
    }
    return;
  }
  int g = bx - nsb;
  int t = threadIdx.x;
  int lane = t & 63, wave = t >> 6;
  int wm = (wave >> 1) * 64, wn = (wave & 1) * 64;
  int quad = lane >> 4, l16 = lane & 15;
  int row0 = (g >> 1) * 128;
  int n0 = (g & 1) * 128;

  f32x4 acc[4][4] = {};

  int eA0 = t, eA1 = t + 256;
  for (int kk = 0; kk < Kp; kk += 32){
    #pragma unroll
    for (int rep = 0; rep < 2; ++rep){
      int e = rep ? eA1 : eA0;
      int r = e >> 2, s = e & 3;
      int grow = row0 + r;
      uint4 va = make_uint4(0, 0, 0, 0);
      if (grow < M) va = *(const uint4*)(A + (size_t)grow * Kp + kk + s * 8);
      *(uint4*)&As[r * LDST + s * 8] = va;
      uint4 vb = *(const uint4*)(Bt + (size_t)(n0 + r) * Kp + kk + s * 8);
      *(uint4*)&Bs[r * LDST + s * 8] = vb;
    }
    __syncthreads();
    bf16x8 af[4], bfr[4];
    #pragma unroll
    for (int i = 0; i < 4; ++i)
      af[i] = *(const bf16x8*)&As[(wm + i * 16 + l16) * LDST + quad * 8];
    #pragma unroll
    for (int j = 0; j < 4; ++j)
      bfr[j] = *(const bf16x8*)&Bs[(wn + j * 16 + l16) * LDST + quad * 8];
    #pragma unroll
    for (int i = 0; i < 4; ++i)
      #pragma unroll
      for (int j = 0; j < 4; ++j)
        acc[i][j] = __builtin_amdgcn_mfma_f32_16x16x32_bf16(af[i], bfr[j], acc[i][j], 0, 0, 0);
    __syncthreads();
  }

  if (POSC){
    float uu[4], vv[4], ww[4];
    #pragma unroll
    for (int j = 0; j < 4; ++j){
      int col = n0 + wn + j * 16 + l16;
      uu[j] = uvw[col]; vv[j] = uvw[256 + col]; ww[j] = uvw[512 + col];
    }
    #pragma unroll
    for (int i = 0; i < 4; ++i){
      #pragma unroll
      for (int r = 0; r < 4; ++r){
        int row = row0 + wm + i * 16 + quad * 4 + r;
        if (row < M){
          int b = batch[row];
          int st = starts[b];
          int cc = starts[b + 1] - st;
          int g2 = (int)ceilf(sqrtf((float)cc));
          int dd = g2 - 1; if (dd < 1) dd = 1;
          float idn = 1.0f / (float)dd;
          int ii = row - st;
          int irow = ii / g2;
          int icol = ii - irow * g2;
          float rn = (float)irow * idn, cn = (float)icol * idn;
          #pragma unroll
          for (int j = 0; j < 4; ++j)
            acc[i][j][r] += rn * uu[j] + cn * vv[j] + ww[j];
        }
      }
    }
  }

  // C store: C/D layout col=lane&15, row=quad*4+reg
  #pragma unroll
  for (int i = 0; i < 4; ++i){
    int rbase = row0 + wm + i * 16 + quad * 4;
    #pragma unroll
    for (int j = 0; j < 4; ++j){
      int col = n0 + wn + j * 16 + l16;
      #pragma unroll
      for (int r = 0; r < 4; ++r){
        int row = rbase + r;
        if (row < M) C[(size_t)row * 256 + col] = f2bf(acc[i][j][r]);
      }
    }
  }
  // fused alphas: this wave's columns n0+wn..+63 == head hda
  int hda = (n0 + wn) >> 6;
  float asw[4], adw[4];
  #pragma unroll
  for (int j = 0; j < 4; ++j){
    int c = n0 + wn + j * 16 + l16;
    asw[j] = a_src[c];
    adw[j] = a_dst[c];
  }
  #pragma unroll
  for (int i = 0; i < 4; ++i){
    #pragma unroll
    for (int r = 0; r < 4; ++r){
      int row = row0 + wm + i * 16 + quad * 4 + r;
      float ps = acc[i][0][r] * asw[0] + acc[i][1][r] * asw[1]
               + acc[i][2][r] * asw[2] + acc[i][3][r] * asw[3];
      float pd = acc[i][0][r] * adw[0] + acc[i][1][r] * adw[1]
               + acc[i][2][r] * adw[2] + acc[i][3][r] * adw[3];
      ps += __shfl_xor(ps, 1); ps += __shfl_xor(ps, 2);
      ps += __shfl_xor(ps, 4); ps += __shfl_xor(ps, 8);
      pd += __shfl_xor(pd, 1); pd += __shfl_xor(pd, 2);
      pd += __shfl_xor(pd, 4); pd += __shfl_xor(pd, 8);
      if (l16 == 0 && row < M){
        alpS[row * 4 + hda] = ps;
        alpD[row * 4 + hda] = pd;
      }
    }
  }
}

// ---- GAT aggregation (R9 core, KNODES=2/wave) + amortized BN-stats epilogue -
__global__ __launch_bounds__(256) void k_aggregate(const unsigned short* __restrict__ hlin,
                                                   const float* __restrict__ alpS,
                                                   const float* __restrict__ alpD,
                                                   const int* __restrict__ cnt,
                                                   const int* __restrict__ csr_src,
                                                   const float* __restrict__ bias,
                                                   unsigned short* __restrict__ outb,
                                                   float* __restrict__ bnP, int N){
  __shared__ float rs[4][256];
  __shared__ float rq[4][256];
  int wv = threadIdx.x >> 6;
  int lane = threadIdx.x & 63;
  int hd = lane >> 4;          // channel-domain head
  int hd2 = lane & 3;          // score-domain head
  int eloc = lane >> 2;        // score-domain edge slot 0..15
  const unsigned short* hbase = hlin + (size_t)lane * 4;
  float4 bv = *(const float4*)(bias + lane * 4);

  float s0 = 0.f, s1 = 0.f, s2 = 0.f, s3 = 0.f;
  float q0 = 0.f, q1 = 0.f, q2 = 0.f, q3 = 0.f;

  int nbase = (blockIdx.x * 4 + wv) * KNODES;
  #pragma unroll
  for (int k = 0; k < KNODES; ++k){
    int n = nbase + k;
    if (n >= N) break;               // wave-uniform
    int beg = n << 6;                // DEG_CAP = 64 fixed stride
    int deg = cnt[n];
    int total = deg + 1;             // + implicit self-loop
    float ad2 = alpD[n * 4 + hd2];
    float lsum = 0.f;
    float a0 = 0.f, a1 = 0.f, a2 = 0.f, a3 = 0.f;

    int full = total & ~15;
    for (int base = 0; base < full; base += 16){
      int e = base + eloc;                    // always < total
      int s = (e < deg) ? csr_src[beg + e] : n;
      float xv = alpS[s * 4 + hd2] + ad2;
      float sc = (xv >= 0.f) ? xv : 0.2f * xv;
      float p = __expf(sc);
      lsum += p;
      uint2 v[16];
      #pragma unroll
      for (int j2 = 0; j2 < 16; ++j2){
        int sj = __shfl(s, j2 << 2);
        v[j2] = *(const uint2*)(hbase + (size_t)sj * 256);
      }
      #pragma unroll
      for (int j2 = 0; j2 < 16; ++j2){
        float pj = __shfl(p, (j2 << 2) | hd);
        a0 += pj * __uint_as_float(v[j2].x << 16);
        a1 += pj * __uint_as_float(v[j2].x & 0xFFFF0000u);
        a2 += pj * __uint_as_float(v[j2].y << 16);
        a3 += pj * __uint_as_float(v[j2].y & 0xFFFF0000u);
      }
    }
    int rem = total - full;                   // 0..15
    if (rem){
      int e = full + eloc;
      int s = n;
      float p = 0.f;
      if (eloc < rem){
        if (e < deg) s = csr_src[beg + e];
        float xv = alpS[s * 4 + hd2] + ad2;
        float sc = (xv >= 0.f) ? xv : 0.2f * xv;
        p = __expf(sc);
      }
      lsum += p;
      #pragma unroll
      for (int g = 0; g < 4; ++g){
        if (g * 4 < rem){                     // wave-uniform branch
          uint2 v[4];
          #pragma unroll
          for (int q = 0; q < 4; ++q){
            int j2 = g * 4 + q;
            int sj = __shfl(s, j2 << 2);
            v[q] = *(const uint2*)(hbase + (size_t)sj * 256);
          }
          #pragma unroll
          for (int q = 0; q < 4; ++q){
            int j2 = g * 4 + q;
            float pj = __shfl(p, (j2 << 2) | hd);
            a0 += pj * __uint_as_float(v[q].x << 16);
            a1 += pj * __uint_as_float(v[q].x & 0xFFFF0000u);
            a2 += pj * __uint_as_float(v[q].y << 16);
            a3 += pj * __uint_as_float(v[q].y & 0xFFFF0000u);
          }
        }
      }
    }
    lsum += __shfl_xor(lsum, 4);
    lsum += __shfl_xor(lsum, 8);
    lsum += __shfl_xor(lsum, 16);
    lsum += __shfl_xor(lsum, 32);
    float lh = __shfl(lsum, hd);
    float inv = 1.0f / lh;
    ushort4 o;
    o.x = f2bf(a0 * inv + bv.x);
    o.y = f2bf(a1 * inv + bv.y);
    o.z = f2bf(a2 * inv + bv.z);
    o.w = f2bf(a3 * inv + bv.w);
    *(ushort4*)(outb + (size_t)n * 256 + lane * 4) = o;
    float f0 = bf2f(o.x), f1 = bf2f(o.y), f2 = bf2f(o.z), f3 = bf2f(o.w);
    s0 += f0; s1 += f1; s2 += f2; s3 += f3;
    q0 += f0 * f0; q1 += f1 * f1; q2 += f2 * f2; q3 += f3 * f3;
  }

  // once-per-block sliced BN-stats epilogue
  int c0 = lane * 4;
  rs[wv][c0 + 0] = s0; rs[wv][c0 + 1] = s1;
  rs[wv][c0 + 2] = s2; rs[wv][c0 + 3] = s3;
  rq[wv][c0 + 0] = q0; rq[wv][c0 + 1] = q1;
  rq[wv][c0 + 2] = q2; rq[wv][c0 + 3] = q3;
  __syncthreads();
  int t = threadIdx.x;
  float s = rs[0][t] + rs[1][t] + rs[2][t] + rs[3][t];
  float q = rq[0][t] + rq[1][t] + rq[2][t] + rq[3][t];
  float* bp = bnP + (size_t)(blockIdx.x & (NSLICE - 1)) * 512;
  atomicAdd(&bp[t], s);
  atomicAdd(&bp[256 + t], q);
}

// ---- BN apply + ELU (bf16 in -> bf16 out, layer 1); slice-reduce prologue ---
__global__ __launch_bounds__(256) void k_bn_elu_bf16(
    const unsigned short* __restrict__ in, const float* __restrict__ bnP,
    const float* __restrict__ gamma, const float* __restrict__ beta,
    unsigned short* __restrict__ outb, int N, float invN){
  __shared__ float scs[256], shs[256];
  int t = threadIdx.x;
  float s = 0.f, q = 0.f;
  #pragma unroll
  for (int j = 0; j < NSLICE; ++j){
    s += bnP[j * 512 + t];
    q += bnP[j * 512 + 256 + t];
  }
  float mean = s * invN;
  float var = q * invN - mean * mean;
  float inv = rsqrtf(var + 1e-5f);
  float g = gamma[t];
  scs[t] = g * inv;
  shs[t] = beta[t] - mean * g * inv;
  __syncthreads();
  int idx8 = blockIdx.x * blockDim.x + t;             // unit = 8 bf16
  int total8 = N * 32;
  for (; idx8 < total8; idx8 += gridDim.x * blockDim.x){
    int c0 = (idx8 * 8) & 255;
    uint4 raw = *(const uint4*)(in + (size_t)idx8 * 8);
    unsigned int rw[4] = {raw.x, raw.y, raw.z, raw.w};
    uint4 outw;
    unsigned int* ow = (unsigned int*)&outw;
    #pragma unroll
    for (int h = 0; h < 4; ++h){
      unsigned int res = 0;
      #pragma unroll
      for (int k = 0; k < 2; ++k){
        int c = c0 + h * 2 + k;
        unsigned short bits = (unsigned short)((rw[h] >> (16 * k)) & 0xFFFF);
        float y = scs[c] * bf2f(bits) + shs[c];
        y = (y > 0.f) ? y : (__expf(y) - 1.f);
        res |= ((unsigned int)f2bf(y)) << (16 * k);
      }
      ow[h] = res;
    }
    *(uint4*)(outb + (size_t)idx8 * 8) = outw;
  }
}

// ---- BN apply + ELU + mean-pool partials (layer 2); slice-reduce prologue ---
__global__ __launch_bounds__(256) void k_bn_elu_pool(
    const unsigned short* __restrict__ in, const float* __restrict__ bnP,
    const float* __restrict__ gamma, const float* __restrict__ beta,
    const int* __restrict__ batch,
    float* __restrict__ pooled, int N, float invN){
  int t = threadIdx.x;
  float s = 0.f, q = 0.f;
  #pragma unroll
  for (int j = 0; j < NSLICE; ++j){
    s += bnP[j * 512 + t];
    q += bnP[j * 512 + 256 + t];
  }
  float mean = s * invN;
  float var = q * invN - mean * mean;
  float inv = rsqrtf(var + 1e-5f);
  float g = gamma[t];
  float scl = g * inv;
  float shf = beta[t] - mean * scl;
  int nb = gridDim.x;
  int rows = (N + nb - 1) / nb;
  int r0 = blockIdx.x * rows, r1 = min(r0 + rows, N);
  float acc = 0.f; int cur = -1;
  for (int r = r0; r < r1; ++r){
    float y = scl * bf2f(in[(size_t)r * 256 + t]) + shf;
    y = (y > 0.f) ? y : (__expf(y) - 1.f);
    int b = batch[r];
    if (b != cur){
      if (cur >= 0) atomicAdd(&pooled[cur * 256 + t], acc);
      acc = 0.f; cur = b;
    }
    acc += y;
  }
  if (cur >= 0) atomicAdd(&pooled[cur * 256 + t], acc);
}

// ---- final FC (invcnt from starts) ------------------------------------------
__global__ __launch_bounds__(128) void k_final(const float* __restrict__ pooled,
                                               const int* __restrict__ starts,
                                               const float* __restrict__ W_fc,
                                               const float* __restrict__ b_fc,
                                               float* __restrict__ out){
  __shared__ float pm[256];
  int b = blockIdx.x;
  int t = threadIdx.x;            // 128
  int c = starts[b + 1] - starts[b];
  float ic = (c > 0) ? 1.0f / (float)c : 0.f;
  pm[t] = pooled[b * 256 + t] * ic;
  pm[t + 128] = pooled[b * 256 + t + 128] * ic;
  __syncthreads();
  float acc = b_fc[t];
  #pragma unroll 4
  for (int cc = 0; cc < 256; ++cc) acc += pm[cc] * W_fc[cc * 128 + t];
  out[b * 128 + t] = acc;
}

extern "C" void kernel_launch(void* const* d_in, const int* in_sizes, int n_in,
                              void* d_out, int out_size, void* d_ws, size_t ws_size,
                              hipStream_t stream){
  const float* x      = (const float*)d_in[0];
  const int*   eidx   = (const int*)  d_in[1];
  const int*   batch  = (const int*)  d_in[2];
  const float* W_pos  = (const float*)d_in[3];
  const float* b_pos  = (const float*)d_in[4];
  const float* W1     = (const float*)d_in[5];
  const float* a_src1 = (const float*)d_in[6];
  const float* a_dst1 = (const float*)d_in[7];
  const float* b1     = (const float*)d_in[8];
  const float* gamma1 = (const float*)d_in[9];
  const float* beta1  = (const float*)d_in[10];
  const float* W2     = (const float*)d_in[11];
  const float* a_src2 = (const float*)d_in[12];
  const float* a_dst2 = (const float*)d_in[13];
  const float* b2     = (const float*)d_in[14];
  const float* gamma2 = (const float*)d_in[15];
  const float* beta2  = (const float*)d_in[16];
  const float* W_fc   = (const float*)d_in[17];
  const float* b_fc   = (const float*)d_in[18];
  float* out = (float*)d_out;

  const int N = in_sizes[0] / 128;
  const int E = in_sizes[1] / 2;
  const int* esrc = eidx;
  const int* edst = eidx + E;

  char* w = (char*)d_ws;
  size_t off = 0;
  auto alloc = [&](size_t bytes) -> void* {
    void* p = w + off;
    off = (off + bytes + 255) & ~(size_t)255;
    return p;
  };
  unsigned short* xb   = (unsigned short*)alloc((size_t)N * 128 * 2);  // bf16 x
  unsigned short* X1b  = (unsigned short*)alloc((size_t)N * 256 * 2);  // GEMM out
  unsigned short* A1b  = (unsigned short*)alloc((size_t)N * 256 * 2);  // aggregate out
  unsigned short* X2b  = (unsigned short*)alloc((size_t)N * 256 * 2);  // BN+ELU out (GEMM2 A)
  float* alpS    = (float*)alloc((size_t)N * 4 * 4);
  float* alpD    = (float*)alloc((size_t)N * 4 * 4);
  int*   starts  = (int*)  alloc(65 * 4);
  int*   cnt     = (int*)  alloc((size_t)N * 4);
  int*   csr_src = (int*)  alloc((size_t)N * DEG_CAP * 4);
  float* bnP     = (float*)alloc((size_t)2 * NSLICE * 512 * 4);  // layer1 | layer2
  float* pooled  = (float*)alloc(64 * 256 * 4);
  unsigned short* W1t = (unsigned short*)alloc(256 * 128 * 2);
  unsigned short* W2t = (unsigned short*)alloc(256 * 256 * 2);
  float* uvw = (float*)alloc(3 * 256 * 4);
  float* bnP1 = bnP, *bnP2 = bnP + NSLICE * 512;

  hipMemsetAsync(cnt, 0, (size_t)N * 4, stream);

  const int nfb0 = (N + 255) / 256;                 // starts+zero blocks
  const int nxb = ((N * 128 / 8) + 255) / 256;      // x->bf16 blocks
  const int nsb = (E + 255) / 256;                  // scatter blocks
  const int nGr = (N + 127) / 128;                  // GEMM row-blocks
  const int nbagg = (N + KNODES * 4 - 1) / (KNODES * 4);

  // init: starts + zero + x->bf16 + weight packs + uvw (all independent)
  k_init<<<nfb0 + nxb + 128 + 256 + 1, 256, 0, stream>>>(
      batch, starts, bnP, pooled, x, xb, W_pos, b_pos,
      W1, W2, W1t, W2t, uvw, N, nfb0, nxb);

  const float invN = 1.0f / (float)N;

  // layer 1: GEMM (K=128, pos-correction epilogue) + co-scheduled CSR scatter
  k_mfma_gemm<1><<<nsb + nGr * 2, 256, 0, stream>>>(
      xb, W1t, X1b, a_src1, a_dst1, alpS, alpD, N, 128, uvw, batch, starts,
      nsb, esrc, edst, cnt, csr_src, E);
  k_aggregate<<<nbagg, 256, 0, stream>>>(X1b, alpS, alpD, cnt, csr_src, b1, A1b, bnP1, N);
  k_bn_elu_bf16<<<512, 256, 0, stream>>>(A1b, bnP1, gamma1, beta1, X2b, N, invN);

  // layer 2 (no scatter blocks)
  k_mfma_gemm<0><<<nGr * 2, 256, 0, stream>>>(
      X2b, W2t, X1b, a_src2, a_dst2, alpS, alpD, N, 256, nullptr, nullptr, nullptr,
      0, nullptr, nullptr, nullptr, nullptr, 0);
  k_aggregate<<<nbagg, 256, 0, stream>>>(X1b, alpS, alpD, cnt, csr_src, b2, A1b, bnP2, N);
  k_bn_elu_pool<<<512, 256, 0, stream>>>(A1b, bnP2, gamma2, beta2, batch, pooled, N, invN);

  // fc
  k_final<<<64, 128, 0, stream>>>(pooled, starts, W_fc, b_fc, out);
}

// Round 10
// 416.903 us; speedup vs baseline: 1.0684x; 1.0684x over previous
//
#include <hip/hip_runtime.h>
#include <math.h>

#define POSD 16
#define DEG_CAP 64    // fixed CSR row stride; P(indeg >= 64) ~ 1e-20 for Poisson(16)
#define NSLICE 16     // BN-stat atomic slices: 2048 blocks/16 = 128 serialized/addr
#define AGG_BLOCKS 2048  // persistent aggregate: 8 blocks/CU, grid-stride over groups

typedef __attribute__((ext_vector_type(8))) __bf16 bf16x8;
typedef __attribute__((ext_vector_type(4))) float f32x4;

__device__ __forceinline__ unsigned short f2bf(float f){
  unsigned int u = __float_as_uint(f);
  u += 0x7FFF + ((u >> 16) & 1);          // round-to-nearest-even
  return (unsigned short)(u >> 16);
}
__device__ __forceinline__ float bf2f(unsigned short u){
  return __uint_as_float(((unsigned int)u) << 16);
}

// ---- merged init: zero+starts+CSR scatter | x->bf16 | packs | uvw -----------
__global__ __launch_bounds__(256) void k_init(
    const int* __restrict__ batch, int* __restrict__ starts,
    const int* __restrict__ src, const int* __restrict__ dst,
    int* __restrict__ cnt, int* __restrict__ csr_src,
    float* __restrict__ bnP, float* __restrict__ pooled,
    const float* __restrict__ x, unsigned short* __restrict__ xb,
    const float* __restrict__ W_pos, const float* __restrict__ b_pos,
    const float* __restrict__ W1, const float* __restrict__ W2,
    unsigned short* __restrict__ W1t, unsigned short* __restrict__ W2t,
    float* __restrict__ uvw,
    int N, int E, int nfb, int nxb){
  int bx = blockIdx.x;
  int t = threadIdx.x;
  if (bx < nfb){
    // front: zero bnP/pooled + starts + direct-slot CSR scatter
    int i = bx * 256 + t;
    if (i < 2 * NSLICE * 512) bnP[i] = 0.f;
    if (i < 64 * 256) pooled[i] = 0.f;
    if (i < N){
      int bi = batch[i];
      int bp = (i == 0) ? -1 : batch[i - 1];
      for (int b = bp + 1; b <= bi; ++b) starts[b] = i;
      if (i == N - 1){
        for (int b = bi + 1; b <= 64; ++b) starts[b] = N;
      }
    }
    if (i < E){
      int d = dst[i];
      int slot = atomicAdd(&cnt[d], 1);
      csr_src[(size_t)d * DEG_CAP + slot] = src[i];
    }
  } else if (bx < nfb + nxb){
    // x (fp32 [N,128]) -> xb (bf16 [N,128]); 8 elems per thread
    size_t idx8 = (size_t)(bx - nfb) * 256 + t;     // unit = 8 floats
    if (idx8 * 8 < (size_t)N * 128){
      const float4* xs = (const float4*)(x + idx8 * 8);
      float4 v0 = xs[0], v1 = xs[1];
      ushort4 o0, o1;
      o0.x = f2bf(v0.x); o0.y = f2bf(v0.y); o0.z = f2bf(v0.z); o0.w = f2bf(v0.w);
      o1.x = f2bf(v1.x); o1.y = f2bf(v1.y); o1.z = f2bf(v1.z); o1.w = f2bf(v1.w);
      ushort4* od = (ushort4*)(xb + idx8 * 8);
      od[0] = o0; od[1] = o1;
    }
  } else if (bx < nfb + nxb + 128){
    // pack W1t [256 x 128] bf16 from W1 rows 0..127 (transposed)
    int idx = (bx - nfb - nxb) * 256 + t;
    int n = idx >> 7, k = idx & 127;
    W1t[idx] = f2bf(W1[(size_t)k * 256 + n]);
  } else if (bx < nfb + nxb + 128 + 256){
    // pack W2t [256 x 256] bf16 (transposed)
    int j = (bx - nfb - nxb - 128) * 256 + t;
    int n = j >> 8, k = j & 255;
    W2t[j] = f2bf(W2[(size_t)k * 256 + n]);
  } else {
    // uvw: rank-2 positional projection vectors (fp32, exact)
    float u = 0.f, v = 0.f, wv = 0.f;
    #pragma unroll
    for (int k = 0; k < POSD; ++k){
      float wc = W1[(size_t)(128 + k) * 256 + t];
      u  += W_pos[k] * wc;          // W_pos row 0
      v  += W_pos[POSD + k] * wc;   // W_pos row 1
      wv += b_pos[k] * wc;
    }
    uvw[t] = u; uvw[256 + t] = v; uvw[512 + t] = wv;
  }
}

// ---- bf16 MFMA GEMM + fused attention logits --------------------------------
// POSC: add rank-2 positional correction rn*u + cn*v + w in the epilogue.
#define LDST 40   // LDS row stride in bf16 (2-way bank aliasing; measured ~1.3us, ok)
template<int POSC>
__global__ __launch_bounds__(256) void k_mfma_gemm(
    const unsigned short* __restrict__ A, const unsigned short* __restrict__ Bt,
    unsigned short* __restrict__ C,
    const float* __restrict__ a_src, const float* __restrict__ a_dst,
    float* __restrict__ alpS, float* __restrict__ alpD, int M, int Kp,
    const float* __restrict__ uvw, const int* __restrict__ batch,
    const int* __restrict__ starts){
  __shared__ unsigned short As[128 * LDST];
  __shared__ unsigned short Bs[128 * LDST];
  int t = threadIdx.x;
  int lane = t & 63, wave = t >> 6;
  int wm = (wave >> 1) * 64, wn = (wave & 1) * 64;
  int quad = lane >> 4, l16 = lane & 15;
  int row0 = blockIdx.x * 128;
  int n0 = blockIdx.y * 128;

  f32x4 acc[4][4] = {};

  int eA0 = t, eA1 = t + 256;
  for (int kk = 0; kk < Kp; kk += 32){
    #pragma unroll
    for (int rep = 0; rep < 2; ++rep){
      int e = rep ? eA1 : eA0;
      int r = e >> 2, s = e & 3;
      int grow = row0 + r;
      uint4 va = make_uint4(0, 0, 0, 0);
      if (grow < M) va = *(const uint4*)(A + (size_t)grow * Kp + kk + s * 8);
      *(uint4*)&As[r * LDST + s * 8] = va;
      uint4 vb = *(const uint4*)(Bt + (size_t)(n0 + r) * Kp + kk + s * 8);
      *(uint4*)&Bs[r * LDST + s * 8] = vb;
    }
    __syncthreads();
    bf16x8 af[4], bfr[4];
    #pragma unroll
    for (int i = 0; i < 4; ++i)
      af[i] = *(const bf16x8*)&As[(wm + i * 16 + l16) * LDST + quad * 8];
    #pragma unroll
    for (int j = 0; j < 4; ++j)
      bfr[j] = *(const bf16x8*)&Bs[(wn + j * 16 + l16) * LDST + quad * 8];
    #pragma unroll
    for (int i = 0; i < 4; ++i)
      #pragma unroll
      for (int j = 0; j < 4; ++j)
        acc[i][j] = __builtin_amdgcn_mfma_f32_16x16x32_bf16(af[i], bfr[j], acc[i][j], 0, 0, 0);
    __syncthreads();
  }

  if (POSC){
    float uu[4], vv[4], ww[4];
    #pragma unroll
    for (int j = 0; j < 4; ++j){
      int col = n0 + wn + j * 16 + l16;
      uu[j] = uvw[col]; vv[j] = uvw[256 + col]; ww[j] = uvw[512 + col];
    }
    #pragma unroll
    for (int i = 0; i < 4; ++i){
      #pragma unroll
      for (int r = 0; r < 4; ++r){
        int row = row0 + wm + i * 16 + quad * 4 + r;
        if (row < M){
          int b = batch[row];
          int st = starts[b];
          int cc = starts[b + 1] - st;
          int g2 = (int)ceilf(sqrtf((float)cc));
          int dd = g2 - 1; if (dd < 1) dd = 1;
          float idn = 1.0f / (float)dd;
          int ii = row - st;
          int irow = ii / g2;
          int icol = ii - irow * g2;
          float rn = (float)irow * idn, cn = (float)icol * idn;
          #pragma unroll
          for (int j = 0; j < 4; ++j)
            acc[i][j][r] += rn * uu[j] + cn * vv[j] + ww[j];
        }
      }
    }
  }

  // C store: C/D layout col=lane&15, row=quad*4+reg
  #pragma unroll
  for (int i = 0; i < 4; ++i){
    int rbase = row0 + wm + i * 16 + quad * 4;
    #pragma unroll
    for (int j = 0; j < 4; ++j){
      int col = n0 + wn + j * 16 + l16;
      #pragma unroll
      for (int r = 0; r < 4; ++r){
        int row = rbase + r;
        if (row < M) C[(size_t)row * 256 + col] = f2bf(acc[i][j][r]);
      }
    }
  }
  // fused alphas: this wave's columns n0+wn..+63 == head hda
  int hda = (n0 + wn) >> 6;
  float asw[4], adw[4];
  #pragma unroll
  for (int j = 0; j < 4; ++j){
    int c = n0 + wn + j * 16 + l16;
    asw[j] = a_src[c];
    adw[j] = a_dst[c];
  }
  #pragma unroll
  for (int i = 0; i < 4; ++i){
    #pragma unroll
    for (int r = 0; r < 4; ++r){
      int row = row0 + wm + i * 16 + quad * 4 + r;
      float ps = acc[i][0][r] * asw[0] + acc[i][1][r] * asw[1]
               + acc[i][2][r] * asw[2] + acc[i][3][r] * asw[3];
      float pd = acc[i][0][r] * adw[0] + acc[i][1][r] * adw[1]
               + acc[i][2][r] * adw[2] + acc[i][3][r] * adw[3];
      ps += __shfl_xor(ps, 1); ps += __shfl_xor(ps, 2);
      ps += __shfl_xor(ps, 4); ps += __shfl_xor(ps, 8);
      pd += __shfl_xor(pd, 1); pd += __shfl_xor(pd, 2);
      pd += __shfl_xor(pd, 4); pd += __shfl_xor(pd, 8);
      if (l16 == 0 && row < M){
        alpS[row * 4 + hda] = ps;
        alpD[row * 4 + hda] = pd;
      }
    }
  }
}

// ---- GAT aggregation: PERSISTENT grid-stride (R9 core per node) -------------
// 2048 blocks; each wave strides over ~6 node-groups, BN s/q accumulate in
// registers across iterations, ONE LDS-combine + sliced-atomic epilogue per
// block. Removes the per-group __syncthreads straggler tail (the +9us tax of
// the fused variants) and cuts atomic traffic to 2048*2KB = 4MB.
__global__ __launch_bounds__(256) void k_aggregate(const unsigned short* __restrict__ hlin,
                                                   const float* __restrict__ alpS,
                                                   const float* __restrict__ alpD,
                                                   const int* __restrict__ cnt,
                                                   const int* __restrict__ csr_src,
                                                   const float* __restrict__ bias,
                                                   unsigned short* __restrict__ outb,
                                                   float* __restrict__ bnP,
                                                   int N, int ngroups){
  __shared__ float rs[4][256];
  __shared__ float rq[4][256];
  int wv = threadIdx.x >> 6;
  int lane = threadIdx.x & 63;
  int hd = lane >> 4;          // channel-domain head
  int hd2 = lane & 3;          // score-domain head
  int eloc = lane >> 2;        // score-domain edge slot 0..15
  const unsigned short* hbase = hlin + (size_t)lane * 4;
  float4 bv = *(const float4*)(bias + lane * 4);

  float s0 = 0.f, s1 = 0.f, s2 = 0.f, s3 = 0.f;
  float q0 = 0.f, q1 = 0.f, q2 = 0.f, q3 = 0.f;

  for (int grp = blockIdx.x; grp < ngroups; grp += gridDim.x){
    int n = grp * 4 + wv;
    if (n < N){                      // wave-uniform
      int beg = n << 6;              // DEG_CAP = 64 fixed stride
      int deg = cnt[n];
      int total = deg + 1;           // + implicit self-loop
      float ad2 = alpD[n * 4 + hd2];
      float lsum = 0.f;
      float a0 = 0.f, a1 = 0.f, a2 = 0.f, a3 = 0.f;

      int full = total & ~15;
      for (int base = 0; base < full; base += 16){
        int e = base + eloc;                    // always < total
        int s = (e < deg) ? csr_src[beg + e] : n;
        float xv = alpS[s * 4 + hd2] + ad2;
        float sc = (xv >= 0.f) ? xv : 0.2f * xv;
        float p = __expf(sc);
        lsum += p;
        uint2 v[16];
        #pragma unroll
        for (int j2 = 0; j2 < 16; ++j2){
          int sj = __shfl(s, j2 << 2);
          v[j2] = *(const uint2*)(hbase + (size_t)sj * 256);
        }
        #pragma unroll
        for (int j2 = 0; j2 < 16; ++j2){
          float pj = __shfl(p, (j2 << 2) | hd);
          a0 += pj * __uint_as_float(v[j2].x << 16);
          a1 += pj * __uint_as_float(v[j2].x & 0xFFFF0000u);
          a2 += pj * __uint_as_float(v[j2].y << 16);
          a3 += pj * __uint_as_float(v[j2].y & 0xFFFF0000u);
        }
      }
      int rem = total - full;                   // 0..15
      if (rem){
        int e = full + eloc;
        int s = n;
        float p = 0.f;
        if (eloc < rem){
          if (e < deg) s = csr_src[beg + e];
          float xv = alpS[s * 4 + hd2] + ad2;
          float sc = (xv >= 0.f) ? xv : 0.2f * xv;
          p = __expf(sc);
        }
        lsum += p;
        #pragma unroll
        for (int g = 0; g < 4; ++g){
          if (g * 4 < rem){                     // wave-uniform branch
            uint2 v[4];
            #pragma unroll
            for (int q = 0; q < 4; ++q){
              int j2 = g * 4 + q;
              int sj = __shfl(s, j2 << 2);
              v[q] = *(const uint2*)(hbase + (size_t)sj * 256);
            }
            #pragma unroll
            for (int q = 0; q < 4; ++q){
              int j2 = g * 4 + q;
              float pj = __shfl(p, (j2 << 2) | hd);
              a0 += pj * __uint_as_float(v[q].x << 16);
              a1 += pj * __uint_as_float(v[q].x & 0xFFFF0000u);
              a2 += pj * __uint_as_float(v[q].y << 16);
              a3 += pj * __uint_as_float(v[q].y & 0xFFFF0000u);
            }
          }
        }
      }
      lsum += __shfl_xor(lsum, 4);
      lsum += __shfl_xor(lsum, 8);
      lsum += __shfl_xor(lsum, 16);
      lsum += __shfl_xor(lsum, 32);
      float lh = __shfl(lsum, hd);
      float inv = 1.0f / lh;
      ushort4 o;
      o.x = f2bf(a0 * inv + bv.x);
      o.y = f2bf(a1 * inv + bv.y);
      o.z = f2bf(a2 * inv + bv.z);
      o.w = f2bf(a3 * inv + bv.w);
      *(ushort4*)(outb + (size_t)n * 256 + lane * 4) = o;
      float f0 = bf2f(o.x), f1 = bf2f(o.y), f2 = bf2f(o.z), f3 = bf2f(o.w);
      s0 += f0; s1 += f1; s2 += f2; s3 += f3;
      q0 += f0 * f0; q1 += f1 * f1; q2 += f2 * f2; q3 += f3 * f3;
    }
  }

  // once-per-block sliced BN-stats epilogue
  int c0 = lane * 4;
  rs[wv][c0 + 0] = s0; rs[wv][c0 + 1] = s1;
  rs[wv][c0 + 2] = s2; rs[wv][c0 + 3] = s3;
  rq[wv][c0 + 0] = q0; rq[wv][c0 + 1] = q1;
  rq[wv][c0 + 2] = q2; rq[wv][c0 + 3] = q3;
  __syncthreads();
  int t = threadIdx.x;
  float s = rs[0][t] + rs[1][t] + rs[2][t] + rs[3][t];
  float q = rq[0][t] + rq[1][t] + rq[2][t] + rq[3][t];
  float* bp = bnP + (size_t)(blockIdx.x & (NSLICE - 1)) * 512;
  atomicAdd(&bp[t], s);
  atomicAdd(&bp[256 + t], q);
}

// ---- BN apply + ELU (bf16 in -> bf16 out, layer 1); slice-reduce prologue ---
__global__ __launch_bounds__(256) void k_bn_elu_bf16(
    const unsigned short* __restrict__ in, const float* __restrict__ bnP,
    const float* __restrict__ gamma, const float* __restrict__ beta,
    unsigned short* __restrict__ outb, int N, float invN){
  __shared__ float scs[256], shs[256];
  int t = threadIdx.x;
  float s = 0.f, q = 0.f;
  #pragma unroll
  for (int j = 0; j < NSLICE; ++j){
    s += bnP[j * 512 + t];
    q += bnP[j * 512 + 256 + t];
  }
  float mean = s * invN;
  float var = q * invN - mean * mean;
  float inv = rsqrtf(var + 1e-5f);
  float g = gamma[t];
  scs[t] = g * inv;
  shs[t] = beta[t] - mean * g * inv;
  __syncthreads();
  int idx8 = blockIdx.x * blockDim.x + t;             // unit = 8 bf16
  int total8 = N * 32;
  for (; idx8 < total8; idx8 += gridDim.x * blockDim.x){
    int c0 = (idx8 * 8) & 255;
    uint4 raw = *(const uint4*)(in + (size_t)idx8 * 8);
    unsigned int rw[4] = {raw.x, raw.y, raw.z, raw.w};
    uint4 outw;
    unsigned int* ow = (unsigned int*)&outw;
    #pragma unroll
    for (int h = 0; h < 4; ++h){
      unsigned int res = 0;
      #pragma unroll
      for (int k = 0; k < 2; ++k){
        int c = c0 + h * 2 + k;
        unsigned short bits = (unsigned short)((rw[h] >> (16 * k)) & 0xFFFF);
        float y = scs[c] * bf2f(bits) + shs[c];
        y = (y > 0.f) ? y : (__expf(y) - 1.f);
        res |= ((unsigned int)f2bf(y)) << (16 * k);
      }
      ow[h] = res;
    }
    *(uint4*)(outb + (size_t)idx8 * 8) = outw;
  }
}

// ---- BN apply + ELU + mean-pool partials (layer 2); slice-reduce prologue ---
__global__ __launch_bounds__(256) void k_bn_elu_pool(
    const unsigned short* __restrict__ in, const float* __restrict__ bnP,
    const float* __restrict__ gamma, const float* __restrict__ beta,
    const int* __restrict__ batch,
    float* __restrict__ pooled, int N, float invN){
  int t = threadIdx.x;
  float s = 0.f, q = 0.f;
  #pragma unroll
  for (int j = 0; j < NSLICE; ++j){
    s += bnP[j * 512 + t];
    q += bnP[j * 512 + 256 + t];
  }
  float mean = s * invN;
  float var = q * invN - mean * mean;
  float inv = rsqrtf(var + 1e-5f);
  float g = gamma[t];
  float scl = g * inv;
  float shf = beta[t] - mean * scl;
  int nb = gridDim.x;
  int rows = (N + nb - 1) / nb;
  int r0 = blockIdx.x * rows, r1 = min(r0 + rows, N);
  float acc = 0.f; int cur = -1;
  for (int r = r0; r < r1; ++r){
    float y = scl * bf2f(in[(size_t)r * 256 + t]) + shf;
    y = (y > 0.f) ? y : (__expf(y) - 1.f);
    int b = batch[r];
    if (b != cur){
      if (cur >= 0) atomicAdd(&pooled[cur * 256 + t], acc);
      acc = 0.f; cur = b;
    }
    acc += y;
  }
  if (cur >= 0) atomicAdd(&pooled[cur * 256 + t], acc);
}

// ---- final FC (invcnt from starts) ------------------------------------------
__global__ __launch_bounds__(128) void k_final(const float* __restrict__ pooled,
                                               const int* __restrict__ starts,
                                               const float* __restrict__ W_fc,
                                               const float* __restrict__ b_fc,
                                               float* __restrict__ out){
  __shared__ float pm[256];
  int b = blockIdx.x;
  int t = threadIdx.x;            // 128
  int c = starts[b + 1] - starts[b];
  float ic = (c > 0) ? 1.0f / (float)c : 0.f;
  pm[t] = pooled[b * 256 + t] * ic;
  pm[t + 128] = pooled[b * 256 + t + 128] * ic;
  __syncthreads();
  float acc = b_fc[t];
  #pragma unroll 4
  for (int cc = 0; cc < 256; ++cc) acc += pm[cc] * W_fc[cc * 128 + t];
  out[b * 128 + t] = acc;
}

extern "C" void kernel_launch(void* const* d_in, const int* in_sizes, int n_in,
                              void* d_out, int out_size, void* d_ws, size_t ws_size,
                              hipStream_t stream){
  const float* x      = (const float*)d_in[0];
  const int*   eidx   = (const int*)  d_in[1];
  const int*   batch  = (const int*)  d_in[2];
  const float* W_pos  = (const float*)d_in[3];
  const float* b_pos  = (const float*)d_in[4];
  const float* W1     = (const float*)d_in[5];
  const float* a_src1 = (const float*)d_in[6];
  const float* a_dst1 = (const float*)d_in[7];
  const float* b1     = (const float*)d_in[8];
  const float* gamma1 = (const float*)d_in[9];
  const float* beta1  = (const float*)d_in[10];
  const float* W2     = (const float*)d_in[11];
  const float* a_src2 = (const float*)d_in[12];
  const float* a_dst2 = (const float*)d_in[13];
  const float* b2     = (const float*)d_in[14];
  const float* gamma2 = (const float*)d_in[15];
  const float* beta2  = (const float*)d_in[16];
  const float* W_fc   = (const float*)d_in[17];
  const float* b_fc   = (const float*)d_in[18];
  float* out = (float*)d_out;

  const int N = in_sizes[0] / 128;
  const int E = in_sizes[1] / 2;
  const int* esrc = eidx;
  const int* edst = eidx + E;

  char* w = (char*)d_ws;
  size_t off = 0;
  auto alloc = [&](size_t bytes) -> void* {
    void* p = w + off;
    off = (off + bytes + 255) & ~(size_t)255;
    return p;
  };
  unsigned short* xb   = (unsigned short*)alloc((size_t)N * 128 * 2);  // bf16 x
  unsigned short* X1b  = (unsigned short*)alloc((size_t)N * 256 * 2);  // GEMM out
  unsigned short* A1b  = (unsigned short*)alloc((size_t)N * 256 * 2);  // aggregate out
  unsigned short* X2b  = (unsigned short*)alloc((size_t)N * 256 * 2);  // BN+ELU out (GEMM2 A)
  float* alpS    = (float*)alloc((size_t)N * 4 * 4);
  float* alpD    = (float*)alloc((size_t)N * 4 * 4);
  int*   starts  = (int*)  alloc(65 * 4);
  int*   cnt     = (int*)  alloc((size_t)N * 4);
  int*   csr_src = (int*)  alloc((size_t)N * DEG_CAP * 4);
  float* bnP     = (float*)alloc((size_t)2 * NSLICE * 512 * 4);  // layer1 | layer2
  float* pooled  = (float*)alloc(64 * 256 * 4);
  unsigned short* W1t = (unsigned short*)alloc(256 * 128 * 2);
  unsigned short* W2t = (unsigned short*)alloc(256 * 256 * 2);
  float* uvw = (float*)alloc(3 * 256 * 4);
  float* bnP1 = bnP, *bnP2 = bnP + NSLICE * 512;

  hipMemsetAsync(cnt, 0, (size_t)N * 4, stream);

  const int nfb = (E + 255) / 256;                  // front blocks
  const int nxb = ((N * 128 / 8) + 255) / 256;      // x->bf16 blocks
  const int ngroups = (N + 3) / 4;                  // 4-node groups

  // merged init: front + x->bf16 + weight packs + uvw (all independent)
  k_init<<<nfb + nxb + 128 + 256 + 1, 256, 0, stream>>>(
      batch, starts, esrc, edst, cnt, csr_src, bnP, pooled,
      x, xb, W_pos, b_pos, W1, W2, W1t, W2t, uvw, N, E, nfb, nxb);

  dim3 ggrid((N + 127) / 128, 2);
  const float invN = 1.0f / (float)N;

  // layer 1 (K=128, rank-2 positional correction in epilogue)
  k_mfma_gemm<1><<<ggrid, 256, 0, stream>>>(xb, W1t, X1b, a_src1, a_dst1,
                                            alpS, alpD, N, 128, uvw, batch, starts);
  k_aggregate<<<AGG_BLOCKS, 256, 0, stream>>>(X1b, alpS, alpD, cnt, csr_src, b1,
                                              A1b, bnP1, N, ngroups);
  k_bn_elu_bf16<<<512, 256, 0, stream>>>(A1b, bnP1, gamma1, beta1, X2b, N, invN);

  // layer 2
  k_mfma_gemm<0><<<ggrid, 256, 0, stream>>>(X2b, W2t, X1b, a_src2, a_dst2,
                                            alpS, alpD, N, 256, nullptr, nullptr, nullptr);
  k_aggregate<<<AGG_BLOCKS, 256, 0, stream>>>(X1b, alpS, alpD, cnt, csr_src, b2,
                                              A1b, bnP2, N, ngroups);
  k_bn_elu_pool<<<512, 256, 0, stream>>>(A1b, bnP2, gamma2, beta2, batch, pooled, N, invN);

  // fc
  k_final<<<64, 128, 0, stream>>>(pooled, starts, W_fc, b_fc, out);
}

// Round 11
// 398.770 us; speedup vs baseline: 1.1170x; 1.0455x over previous
//
#include <hip/hip_runtime.h>
#include <math.h>

#define POSD 16
#define DEG_CAP 64    // fixed CSR row stride; P(indeg >= 64) ~ 1e-20 for Poisson(16)
#define NSLICE 16     // BN-stat atomic slices: 2048 blocks/16 = 128 serialized/addr
#define AGG_BLOCKS 2048  // persistent aggregate: 8 blocks/CU, grid-stride over groups

typedef __attribute__((ext_vector_type(8))) __bf16 bf16x8;
typedef __attribute__((ext_vector_type(4))) float f32x4;

__device__ __forceinline__ unsigned short f2bf(float f){
  unsigned int u = __float_as_uint(f);
  u += 0x7FFF + ((u >> 16) & 1);          // round-to-nearest-even
  return (unsigned short)(u >> 16);
}
__device__ __forceinline__ float bf2f(unsigned short u){
  return __uint_as_float(((unsigned int)u) << 16);
}

// ---- merged init: zero+starts+CSR scatter | packs | uvw ---------------------
__global__ __launch_bounds__(256) void k_init(
    const int* __restrict__ batch, int* __restrict__ starts,
    const int* __restrict__ src, const int* __restrict__ dst,
    int* __restrict__ cnt, int* __restrict__ csr_src,
    float* __restrict__ bnP,
    const float* __restrict__ W_pos, const float* __restrict__ b_pos,
    const float* __restrict__ W1, const float* __restrict__ W2,
    unsigned short* __restrict__ W1t, unsigned short* __restrict__ W2t,
    float* __restrict__ uvw,
    int N, int E, int nfb){
  int bx = blockIdx.x;
  int t = threadIdx.x;
  if (bx < nfb){
    // front: zero bnP + starts + direct-slot CSR scatter
    int i = bx * 256 + t;
    if (i < 2 * NSLICE * 512) bnP[i] = 0.f;
    if (i < N){
      int bi = batch[i];
      int bp = (i == 0) ? -1 : batch[i - 1];
      for (int b = bp + 1; b <= bi; ++b) starts[b] = i;
      if (i == N - 1){
        for (int b = bi + 1; b <= 64; ++b) starts[b] = N;
      }
    }
    if (i < E){
      int d = dst[i];
      int slot = atomicAdd(&cnt[d], 1);
      csr_src[(size_t)d * DEG_CAP + slot] = src[i];
    }
  } else if (bx < nfb + 128){
    // pack W1t [256 x 128] bf16 from W1 rows 0..127 (transposed)
    int idx = (bx - nfb) * 256 + t;
    int n = idx >> 7, k = idx & 127;
    W1t[idx] = f2bf(W1[(size_t)k * 256 + n]);
  } else if (bx < nfb + 128 + 256){
    // pack W2t [256 x 256] bf16 (transposed)
    int j = (bx - nfb - 128) * 256 + t;
    int n = j >> 8, k = j & 255;
    W2t[j] = f2bf(W2[(size_t)k * 256 + n]);
  } else {
    // uvw: rank-2 positional projection vectors (fp32, exact)
    float u = 0.f, v = 0.f, wv = 0.f;
    #pragma unroll
    for (int k = 0; k < POSD; ++k){
      float wc = W1[(size_t)(128 + k) * 256 + t];
      u  += W_pos[k] * wc;          // W_pos row 0
      v  += W_pos[POSD + k] * wc;   // W_pos row 1
      wv += b_pos[k] * wc;
    }
    uvw[t] = u; uvw[256 + t] = v; uvw[512 + t] = wv;
  }
}

// ---- bf16 MFMA GEMM + fused attention logits --------------------------------
// POSC=1 (layer 1): A is fp32 x, converted bf16 in-staging (identical rounding
// to the old xb path); rank-2 positional correction added in the epilogue.
// POSC=0 (layer 2): A is bf16.
#define LDST 40   // LDS row stride in bf16 (2-way bank aliasing; measured ~1.3us, ok)
template<int POSC>
__global__ __launch_bounds__(256) void k_mfma_gemm(
    const unsigned short* __restrict__ A, const float* __restrict__ Af,
    const unsigned short* __restrict__ Bt,
    unsigned short* __restrict__ C,
    const float* __restrict__ a_src, const float* __restrict__ a_dst,
    float* __restrict__ alpS, float* __restrict__ alpD, int M, int Kp,
    const float* __restrict__ uvw, const int* __restrict__ batch,
    const int* __restrict__ starts){
  __shared__ unsigned short As[128 * LDST];
  __shared__ unsigned short Bs[128 * LDST];
  int t = threadIdx.x;
  int lane = t & 63, wave = t >> 6;
  int wm = (wave >> 1) * 64, wn = (wave & 1) * 64;
  int quad = lane >> 4, l16 = lane & 15;
  int row0 = blockIdx.x * 128;
  int n0 = blockIdx.y * 128;

  f32x4 acc[4][4] = {};

  int eA0 = t, eA1 = t + 256;
  for (int kk = 0; kk < Kp; kk += 32){
    #pragma unroll
    for (int rep = 0; rep < 2; ++rep){
      int e = rep ? eA1 : eA0;
      int r = e >> 2, s = e & 3;
      int grow = row0 + r;
      if (POSC){
        float4 f0 = make_float4(0.f, 0.f, 0.f, 0.f), f1 = f0;
        if (grow < M){
          const float4* xs = (const float4*)(Af + (size_t)grow * Kp + kk + s * 8);
          f0 = xs[0]; f1 = xs[1];
        }
        ushort4 o0, o1;
        o0.x = f2bf(f0.x); o0.y = f2bf(f0.y); o0.z = f2bf(f0.z); o0.w = f2bf(f0.w);
        o1.x = f2bf(f1.x); o1.y = f2bf(f1.y); o1.z = f2bf(f1.z); o1.w = f2bf(f1.w);
        *(ushort4*)&As[r * LDST + s * 8] = o0;
        *(ushort4*)&As[r * LDST + s * 8 + 4] = o1;
      } else {
        uint4 va = make_uint4(0, 0, 0, 0);
        if (grow < M) va = *(const uint4*)(A + (size_t)grow * Kp + kk + s * 8);
        *(uint4*)&As[r * LDST + s * 8] = va;
      }
      uint4 vb = *(const uint4*)(Bt + (size_t)(n0 + r) * Kp + kk + s * 8);
      *(uint4*)&Bs[r * LDST + s * 8] = vb;
    }
    __syncthreads();
    bf16x8 af[4], bfr[4];
    #pragma unroll
    for (int i = 0; i < 4; ++i)
      af[i] = *(const bf16x8*)&As[(wm + i * 16 + l16) * LDST + quad * 8];
    #pragma unroll
    for (int j = 0; j < 4; ++j)
      bfr[j] = *(const bf16x8*)&Bs[(wn + j * 16 + l16) * LDST + quad * 8];
    #pragma unroll
    for (int i = 0; i < 4; ++i)
      #pragma unroll
      for (int j = 0; j < 4; ++j)
        acc[i][j] = __builtin_amdgcn_mfma_f32_16x16x32_bf16(af[i], bfr[j], acc[i][j], 0, 0, 0);
    __syncthreads();
  }

  if (POSC){
    float uu[4], vv[4], ww[4];
    #pragma unroll
    for (int j = 0; j < 4; ++j){
      int col = n0 + wn + j * 16 + l16;
      uu[j] = uvw[col]; vv[j] = uvw[256 + col]; ww[j] = uvw[512 + col];
    }
    #pragma unroll
    for (int i = 0; i < 4; ++i){
      #pragma unroll
      for (int r = 0; r < 4; ++r){
        int row = row0 + wm + i * 16 + quad * 4 + r;
        if (row < M){
          int b = batch[row];
          int st = starts[b];
          int cc = starts[b + 1] - st;
          int g2 = (int)ceilf(sqrtf((float)cc));
          int dd = g2 - 1; if (dd < 1) dd = 1;
          float idn = 1.0f / (float)dd;
          int ii = row - st;
          int irow = ii / g2;
          int icol = ii - irow * g2;
          float rn = (float)irow * idn, cn = (float)icol * idn;
          #pragma unroll
          for (int j = 0; j < 4; ++j)
            acc[i][j][r] += rn * uu[j] + cn * vv[j] + ww[j];
        }
      }
    }
  }

  // C store: C/D layout col=lane&15, row=quad*4+reg
  #pragma unroll
  for (int i = 0; i < 4; ++i){
    int rbase = row0 + wm + i * 16 + quad * 4;
    #pragma unroll
    for (int j = 0; j < 4; ++j){
      int col = n0 + wn + j * 16 + l16;
      #pragma unroll
      for (int r = 0; r < 4; ++r){
        int row = rbase + r;
        if (row < M) C[(size_t)row * 256 + col] = f2bf(acc[i][j][r]);
      }
    }
  }
  // fused alphas: this wave's columns n0+wn..+63 == head hda
  int hda = (n0 + wn) >> 6;
  float asw[4], adw[4];
  #pragma unroll
  for (int j = 0; j < 4; ++j){
    int c = n0 + wn + j * 16 + l16;
    asw[j] = a_src[c];
    adw[j] = a_dst[c];
  }
  #pragma unroll
  for (int i = 0; i < 4; ++i){
    #pragma unroll
    for (int r = 0; r < 4; ++r){
      int row = row0 + wm + i * 16 + quad * 4 + r;
      float ps = acc[i][0][r] * asw[0] + acc[i][1][r] * asw[1]
               + acc[i][2][r] * asw[2] + acc[i][3][r] * asw[3];
      float pd = acc[i][0][r] * adw[0] + acc[i][1][r] * adw[1]
               + acc[i][2][r] * adw[2] + acc[i][3][r] * adw[3];
      ps += __shfl_xor(ps, 1); ps += __shfl_xor(ps, 2);
      ps += __shfl_xor(ps, 4); ps += __shfl_xor(ps, 8);
      pd += __shfl_xor(pd, 1); pd += __shfl_xor(pd, 2);
      pd += __shfl_xor(pd, 4); pd += __shfl_xor(pd, 8);
      if (l16 == 0 && row < M){
        alpS[row * 4 + hda] = ps;
        alpD[row * 4 + hda] = pd;
      }
    }
  }
}

// ---- GAT aggregation: PERSISTENT grid-stride (R9 core per node) -------------
__global__ __launch_bounds__(256) void k_aggregate(const unsigned short* __restrict__ hlin,
                                                   const float* __restrict__ alpS,
                                                   const float* __restrict__ alpD,
                                                   const int* __restrict__ cnt,
                                                   const int* __restrict__ csr_src,
                                                   const float* __restrict__ bias,
                                                   unsigned short* __restrict__ outb,
                                                   float* __restrict__ bnP,
                                                   int N, int ngroups){
  __shared__ float rs[4][256];
  __shared__ float rq[4][256];
  int wv = threadIdx.x >> 6;
  int lane = threadIdx.x & 63;
  int hd = lane >> 4;          // channel-domain head
  int hd2 = lane & 3;          // score-domain head
  int eloc = lane >> 2;        // score-domain edge slot 0..15
  const unsigned short* hbase = hlin + (size_t)lane * 4;
  float4 bv = *(const float4*)(bias + lane * 4);

  float s0 = 0.f, s1 = 0.f, s2 = 0.f, s3 = 0.f;
  float q0 = 0.f, q1 = 0.f, q2 = 0.f, q3 = 0.f;

  for (int grp = blockIdx.x; grp < ngroups; grp += gridDim.x){
    int n = grp * 4 + wv;
    if (n < N){                      // wave-uniform
      int beg = n << 6;              // DEG_CAP = 64 fixed stride
      int deg = cnt[n];
      int total = deg + 1;           // + implicit self-loop
      float ad2 = alpD[n * 4 + hd2];
      float lsum = 0.f;
      float a0 = 0.f, a1 = 0.f, a2 = 0.f, a3 = 0.f;

      int full = total & ~15;
      for (int base = 0; base < full; base += 16){
        int e = base + eloc;                    // always < total
        int s = (e < deg) ? csr_src[beg + e] : n;
        float xv = alpS[s * 4 + hd2] + ad2;
        float sc = (xv >= 0.f) ? xv : 0.2f * xv;
        float p = __expf(sc);
        lsum += p;
        uint2 v[16];
        #pragma unroll
        for (int j2 = 0; j2 < 16; ++j2){
          int sj = __shfl(s, j2 << 2);
          v[j2] = *(const uint2*)(hbase + (size_t)sj * 256);
        }
        #pragma unroll
        for (int j2 = 0; j2 < 16; ++j2){
          float pj = __shfl(p, (j2 << 2) | hd);
          a0 += pj * __uint_as_float(v[j2].x << 16);
          a1 += pj * __uint_as_float(v[j2].x & 0xFFFF0000u);
          a2 += pj * __uint_as_float(v[j2].y << 16);
          a3 += pj * __uint_as_float(v[j2].y & 0xFFFF0000u);
        }
      }
      int rem = total - full;                   // 0..15
      if (rem){
        int e = full + eloc;
        int s = n;
        float p = 0.f;
        if (eloc < rem){
          if (e < deg) s = csr_src[beg + e];
          float xv = alpS[s * 4 + hd2] + ad2;
          float sc = (xv >= 0.f) ? xv : 0.2f * xv;
          p = __expf(sc);
        }
        lsum += p;
        #pragma unroll
        for (int g = 0; g < 4; ++g){
          if (g * 4 < rem){                     // wave-uniform branch
            uint2 v[4];
            #pragma unroll
            for (int q = 0; q < 4; ++q){
              int j2 = g * 4 + q;
              int sj = __shfl(s, j2 << 2);
              v[q] = *(const uint2*)(hbase + (size_t)sj * 256);
            }
            #pragma unroll
            for (int q = 0; q < 4; ++q){
              int j2 = g * 4 + q;
              float pj = __shfl(p, (j2 << 2) | hd);
              a0 += pj * __uint_as_float(v[q].x << 16);
              a1 += pj * __uint_as_float(v[q].x & 0xFFFF0000u);
              a2 += pj * __uint_as_float(v[q].y << 16);
              a3 += pj * __uint_as_float(v[q].y & 0xFFFF0000u);
            }
          }
        }
      }
      lsum += __shfl_xor(lsum, 4);
      lsum += __shfl_xor(lsum, 8);
      lsum += __shfl_xor(lsum, 16);
      lsum += __shfl_xor(lsum, 32);
      float lh = __shfl(lsum, hd);
      float inv = 1.0f / lh;
      ushort4 o;
      o.x = f2bf(a0 * inv + bv.x);
      o.y = f2bf(a1 * inv + bv.y);
      o.z = f2bf(a2 * inv + bv.z);
      o.w = f2bf(a3 * inv + bv.w);
      *(ushort4*)(outb + (size_t)n * 256 + lane * 4) = o;
      float f0 = bf2f(o.x), f1 = bf2f(o.y), f2 = bf2f(o.z), f3 = bf2f(o.w);
      s0 += f0; s1 += f1; s2 += f2; s3 += f3;
      q0 += f0 * f0; q1 += f1 * f1; q2 += f2 * f2; q3 += f3 * f3;
    }
  }

  // once-per-block sliced BN-stats epilogue
  int c0 = lane * 4;
  rs[wv][c0 + 0] = s0; rs[wv][c0 + 1] = s1;
  rs[wv][c0 + 2] = s2; rs[wv][c0 + 3] = s3;
  rq[wv][c0 + 0] = q0; rq[wv][c0 + 1] = q1;
  rq[wv][c0 + 2] = q2; rq[wv][c0 + 3] = q3;
  __syncthreads();
  int t = threadIdx.x;
  float s = rs[0][t] + rs[1][t] + rs[2][t] + rs[3][t];
  float q = rq[0][t] + rq[1][t] + rq[2][t] + rq[3][t];
  float* bp = bnP + (size_t)(blockIdx.x & (NSLICE - 1)) * 512;
  atomicAdd(&bp[t], s);
  atomicAdd(&bp[256 + t], q);
}

// ---- BN apply + ELU (bf16 in -> bf16 out, layer 1); slice-reduce prologue ---
__global__ __launch_bounds__(256) void k_bn_elu_bf16(
    const unsigned short* __restrict__ in, const float* __restrict__ bnP,
    const float* __restrict__ gamma, const float* __restrict__ beta,
    unsigned short* __restrict__ outb, int N, float invN){
  __shared__ float scs[256], shs[256];
  int t = threadIdx.x;
  float s = 0.f, q = 0.f;
  #pragma unroll
  for (int j = 0; j < NSLICE; ++j){
    s += bnP[j * 512 + t];
    q += bnP[j * 512 + 256 + t];
  }
  float mean = s * invN;
  float var = q * invN - mean * mean;
  float inv = rsqrtf(var + 1e-5f);
  float g = gamma[t];
  scs[t] = g * inv;
  shs[t] = beta[t] - mean * g * inv;
  __syncthreads();
  int idx8 = blockIdx.x * blockDim.x + t;             // unit = 8 bf16
  int total8 = N * 32;
  for (; idx8 < total8; idx8 += gridDim.x * blockDim.x){
    int c0 = (idx8 * 8) & 255;
    uint4 raw = *(const uint4*)(in + (size_t)idx8 * 8);
    unsigned int rw[4] = {raw.x, raw.y, raw.z, raw.w};
    uint4 outw;
    unsigned int* ow = (unsigned int*)&outw;
    #pragma unroll
    for (int h = 0; h < 4; ++h){
      unsigned int res = 0;
      #pragma unroll
      for (int k = 0; k < 2; ++k){
        int c = c0 + h * 2 + k;
        unsigned short bits = (unsigned short)((rw[h] >> (16 * k)) & 0xFFFF);
        float y = scs[c] * bf2f(bits) + shs[c];
        y = (y > 0.f) ? y : (__expf(y) - 1.f);
        res |= ((unsigned int)f2bf(y)) << (16 * k);
      }
      ow[h] = res;
    }
    *(uint4*)(outb + (size_t)idx8 * 8) = outw;
  }
}

// ---- tail: BN+ELU + mean-pool + final FC, one block per graph ---------------
// Rows of a graph are contiguous (starts); 1024 threads = 4-way row parallel
// x 256 channels. No pooled buffer, no atomics, no separate FC dispatch.
__global__ __launch_bounds__(1024) void k_tail(
    const unsigned short* __restrict__ in, const float* __restrict__ bnP,
    const float* __restrict__ gamma, const float* __restrict__ beta,
    const int* __restrict__ starts, const float* __restrict__ W_fc,
    const float* __restrict__ b_fc, float* __restrict__ out, float invN){
  __shared__ float pm[4][256];
  __shared__ float scs[256], shs[256];
  int t = threadIdx.x;
  int c = t & 255;        // channel
  int seg = t >> 8;       // row segment 0..3
  if (t < 256){
    float s = 0.f, q = 0.f;
    #pragma unroll
    for (int j = 0; j < NSLICE; ++j){
      s += bnP[j * 512 + t];
      q += bnP[j * 512 + 256 + t];
    }
    float mean = s * invN;
    float var = q * invN - mean * mean;
    float inv = rsqrtf(var + 1e-5f);
    float g = gamma[t];
    scs[t] = g * inv;
    shs[t] = beta[t] - mean * g * inv;
  }
  __syncthreads();
  int b = blockIdx.x;
  int r0 = starts[b], r1 = starts[b + 1];
  float scl = scs[c], shf = shs[c];
  float acc = 0.f;
  #pragma unroll 4
  for (int r = r0 + seg; r < r1; r += 4){
    float y = scl * bf2f(in[(size_t)r * 256 + c]) + shf;
    y = (y > 0.f) ? y : (__expf(y) - 1.f);
    acc += y;
  }
  pm[seg][c] = acc;
  __syncthreads();
  if (t < 256){
    int cnt = r1 - r0;
    float ic = (cnt > 0) ? 1.0f / (float)cnt : 0.f;
    pm[0][t] = (pm[0][t] + pm[1][t] + pm[2][t] + pm[3][t]) * ic;
  }
  __syncthreads();
  if (t < 128){
    float a = b_fc[t];
    #pragma unroll 4
    for (int cc = 0; cc < 256; ++cc) a += pm[0][cc] * W_fc[cc * 128 + t];
    out[b * 128 + t] = a;
  }
}

extern "C" void kernel_launch(void* const* d_in, const int* in_sizes, int n_in,
                              void* d_out, int out_size, void* d_ws, size_t ws_size,
                              hipStream_t stream){
  const float* x      = (const float*)d_in[0];
  const int*   eidx   = (const int*)  d_in[1];
  const int*   batch  = (const int*)  d_in[2];
  const float* W_pos  = (const float*)d_in[3];
  const float* b_pos  = (const float*)d_in[4];
  const float* W1     = (const float*)d_in[5];
  const float* a_src1 = (const float*)d_in[6];
  const float* a_dst1 = (const float*)d_in[7];
  const float* b1     = (const float*)d_in[8];
  const float* gamma1 = (const float*)d_in[9];
  const float* beta1  = (const float*)d_in[10];
  const float* W2     = (const float*)d_in[11];
  const float* a_src2 = (const float*)d_in[12];
  const float* a_dst2 = (const float*)d_in[13];
  const float* b2     = (const float*)d_in[14];
  const float* gamma2 = (const float*)d_in[15];
  const float* beta2  = (const float*)d_in[16];
  const float* W_fc   = (const float*)d_in[17];
  const float* b_fc   = (const float*)d_in[18];
  float* out = (float*)d_out;

  const int N = in_sizes[0] / 128;
  const int E = in_sizes[1] / 2;
  const int* esrc = eidx;
  const int* edst = eidx + E;

  char* w = (char*)d_ws;
  size_t off = 0;
  auto alloc = [&](size_t bytes) -> void* {
    void* p = w + off;
    off = (off + bytes + 255) & ~(size_t)255;
    return p;
  };
  unsigned short* X1b  = (unsigned short*)alloc((size_t)N * 256 * 2);  // GEMM out
  unsigned short* A1b  = (unsigned short*)alloc((size_t)N * 256 * 2);  // aggregate out
  unsigned short* X2b  = (unsigned short*)alloc((size_t)N * 256 * 2);  // BN+ELU out (GEMM2 A)
  float* alpS    = (float*)alloc((size_t)N * 4 * 4);
  float* alpD    = (float*)alloc((size_t)N * 4 * 4);
  int*   starts  = (int*)  alloc(65 * 4);
  int*   cnt     = (int*)  alloc((size_t)N * 4);
  int*   csr_src = (int*)  alloc((size_t)N * DEG_CAP * 4);
  float* bnP     = (float*)alloc((size_t)2 * NSLICE * 512 * 4);  // layer1 | layer2
  unsigned short* W1t = (unsigned short*)alloc(256 * 128 * 2);
  unsigned short* W2t = (unsigned short*)alloc(256 * 256 * 2);
  float* uvw = (float*)alloc(3 * 256 * 4);
  float* bnP1 = bnP, *bnP2 = bnP + NSLICE * 512;

  hipMemsetAsync(cnt, 0, (size_t)N * 4, stream);

  const int nfb = (E + 255) / 256;                  // front blocks
  const int ngroups = (N + 3) / 4;                  // 4-node groups

  // merged init: front + weight packs + uvw (all independent)
  k_init<<<nfb + 128 + 256 + 1, 256, 0, stream>>>(
      batch, starts, esrc, edst, cnt, csr_src, bnP,
      W_pos, b_pos, W1, W2, W1t, W2t, uvw, N, E, nfb);

  dim3 ggrid((N + 127) / 128, 2);
  const float invN = 1.0f / (float)N;

  // layer 1 (K=128, fp32-A in-staging convert, pos-correction epilogue)
  k_mfma_gemm<1><<<ggrid, 256, 0, stream>>>(nullptr, x, W1t, X1b, a_src1, a_dst1,
                                            alpS, alpD, N, 128, uvw, batch, starts);
  k_aggregate<<<AGG_BLOCKS, 256, 0, stream>>>(X1b, alpS, alpD, cnt, csr_src, b1,
                                              A1b, bnP1, N, ngroups);
  k_bn_elu_bf16<<<512, 256, 0, stream>>>(A1b, bnP1, gamma1, beta1, X2b, N, invN);

  // layer 2
  k_mfma_gemm<0><<<ggrid, 256, 0, stream>>>(X2b, nullptr, W2t, X1b, a_src2, a_dst2,
                                            alpS, alpD, N, 256, nullptr, nullptr, nullptr);
  k_aggregate<<<AGG_BLOCKS, 256, 0, stream>>>(X1b, alpS, alpD, cnt, csr_src, b2,
                                              A1b, bnP2, N, ngroups);

  // tail: BN+ELU + mean-pool + FC (one block per graph)
  k_tail<<<64, 1024, 0, stream>>>(A1b, bnP2, gamma2, beta2, starts, W_fc, b_fc,
                                  out, invN);
}

// Round 12
// 393.108 us; speedup vs baseline: 1.1331x; 1.0144x over previous
//
#include <hip/hip_runtime.h>
#include <math.h>

#define POSD 16
#define DEG_CAP 64    // fixed CSR row stride; P(indeg >= 64) ~ 1e-20 for Poisson(16)
#define NSLICE 16     // BN-stat atomic slices: 2048 blocks/16 = 128 serialized/addr
#define AGG_BLOCKS 2048  // persistent aggregate: 8 blocks/CU, grid-stride over groups

typedef __attribute__((ext_vector_type(8))) __bf16 bf16x8;
typedef __attribute__((ext_vector_type(4))) float f32x4;

__device__ __forceinline__ unsigned short f2bf(float f){
  unsigned int u = __float_as_uint(f);
  u += 0x7FFF + ((u >> 16) & 1);          // round-to-nearest-even
  return (unsigned short)(u >> 16);
}
__device__ __forceinline__ float bf2f(unsigned short u){
  return __uint_as_float(((unsigned int)u) << 16);
}

// ---- merged init: zero+starts+CSR scatter | packs | uvw ---------------------
__global__ __launch_bounds__(256) void k_init(
    const int* __restrict__ batch, int* __restrict__ starts,
    const int* __restrict__ src, const int* __restrict__ dst,
    int* __restrict__ cnt, int* __restrict__ csr_src,
    float* __restrict__ bnP,
    const float* __restrict__ W_pos, const float* __restrict__ b_pos,
    const float* __restrict__ W1, const float* __restrict__ W2,
    unsigned short* __restrict__ W1t, unsigned short* __restrict__ W2t,
    float* __restrict__ uvw,
    int N, int E, int nfb){
  int bx = blockIdx.x;
  int t = threadIdx.x;
  if (bx < nfb){
    // front: zero bnP + starts + direct-slot CSR scatter
    int i = bx * 256 + t;
    if (i < 2 * NSLICE * 512) bnP[i] = 0.f;
    if (i < N){
      int bi = batch[i];
      int bp = (i == 0) ? -1 : batch[i - 1];
      for (int b = bp + 1; b <= bi; ++b) starts[b] = i;
      if (i == N - 1){
        for (int b = bi + 1; b <= 64; ++b) starts[b] = N;
      }
    }
    if (i < E){
      int d = dst[i];
      int slot = atomicAdd(&cnt[d], 1);
      csr_src[(size_t)d * DEG_CAP + slot] = src[i];
    }
  } else if (bx < nfb + 128){
    // pack W1t [256 x 128] bf16 from W1 rows 0..127 (transposed)
    int idx = (bx - nfb) * 256 + t;
    int n = idx >> 7, k = idx & 127;
    W1t[idx] = f2bf(W1[(size_t)k * 256 + n]);
  } else if (bx < nfb + 128 + 256){
    // pack W2t [256 x 256] bf16 (transposed)
    int j = (bx - nfb - 128) * 256 + t;
    int n = j >> 8, k = j & 255;
    W2t[j] = f2bf(W2[(size_t)k * 256 + n]);
  } else {
    // uvw: rank-2 positional projection vectors (fp32, exact)
    float u = 0.f, v = 0.f, wv = 0.f;
    #pragma unroll
    for (int k = 0; k < POSD; ++k){
      float wc = W1[(size_t)(128 + k) * 256 + t];
      u  += W_pos[k] * wc;          // W_pos row 0
      v  += W_pos[POSD + k] * wc;   // W_pos row 1
      wv += b_pos[k] * wc;
    }
    uvw[t] = u; uvw[256 + t] = v; uvw[512 + t] = wv;
  }
}

// ---- bf16 MFMA GEMM + fused attention logits --------------------------------
// MODE 0 (layer 1): A is fp32 x, converted bf16 in-staging; rank-2 positional
//                   correction (uvw, batch, starts) added in the epilogue.
// MODE 1 (layer 2): A is bf16 raw aggregate output; BN1+ELU applied in-staging
//                   (scale/shift from sliced bnP stats; identical rounding to
//                   the old standalone k_bn_elu_bf16 pass).
#define LDST 40   // LDS row stride in bf16 (2-way bank aliasing; measured ~1.3us, ok)
template<int MODE>
__global__ __launch_bounds__(256) void k_mfma_gemm(
    const unsigned short* __restrict__ A, const float* __restrict__ Af,
    const unsigned short* __restrict__ Bt,
    unsigned short* __restrict__ C,
    const float* __restrict__ a_src, const float* __restrict__ a_dst,
    float* __restrict__ alpS, float* __restrict__ alpD, int M, int Kp,
    const float* __restrict__ uvw, const int* __restrict__ batch,
    const int* __restrict__ starts,
    const float* __restrict__ bnP, const float* __restrict__ gamma,
    const float* __restrict__ beta, float invN){
  __shared__ unsigned short As[128 * LDST];
  __shared__ unsigned short Bs[128 * LDST];
  __shared__ float bn_sc[256];
  __shared__ float bn_sh[256];
  int t = threadIdx.x;
  int lane = t & 63, wave = t >> 6;
  int wm = (wave >> 1) * 64, wn = (wave & 1) * 64;
  int quad = lane >> 4, l16 = lane & 15;
  int row0 = blockIdx.x * 128;
  int n0 = blockIdx.y * 128;

  if (MODE == 1){
    // slice-reduce BN1 stats -> per-channel scale/shift
    float s = 0.f, q = 0.f;
    #pragma unroll
    for (int j = 0; j < NSLICE; ++j){
      s += bnP[j * 512 + t];
      q += bnP[j * 512 + 256 + t];
    }
    float mean = s * invN;
    float var = q * invN - mean * mean;
    float inv = rsqrtf(var + 1e-5f);
    float g = gamma[t];
    bn_sc[t] = g * inv;
    bn_sh[t] = beta[t] - mean * g * inv;
    __syncthreads();
  }

  f32x4 acc[4][4] = {};

  int eA0 = t, eA1 = t + 256;
  for (int kk = 0; kk < Kp; kk += 32){
    #pragma unroll
    for (int rep = 0; rep < 2; ++rep){
      int e = rep ? eA1 : eA0;
      int r = e >> 2, s = e & 3;
      int grow = row0 + r;
      if (MODE == 0){
        float4 f0 = make_float4(0.f, 0.f, 0.f, 0.f), f1 = f0;
        if (grow < M){
          const float4* xs = (const float4*)(Af + (size_t)grow * Kp + kk + s * 8);
          f0 = xs[0]; f1 = xs[1];
        }
        ushort4 o0, o1;
        o0.x = f2bf(f0.x); o0.y = f2bf(f0.y); o0.z = f2bf(f0.z); o0.w = f2bf(f0.w);
        o1.x = f2bf(f1.x); o1.y = f2bf(f1.y); o1.z = f2bf(f1.z); o1.w = f2bf(f1.w);
        *(ushort4*)&As[r * LDST + s * 8] = o0;
        *(ushort4*)&As[r * LDST + s * 8 + 4] = o1;
      } else {
        uint4 va = make_uint4(0, 0, 0, 0);
        if (grow < M) va = *(const uint4*)(A + (size_t)grow * Kp + kk + s * 8);
        unsigned int* wvp = (unsigned int*)&va;
        int cbase = kk + s * 8;
        #pragma unroll
        for (int h = 0; h < 4; ++h){
          unsigned int res = 0;
          #pragma unroll
          for (int kb = 0; kb < 2; ++kb){
            int cc = cbase + h * 2 + kb;
            float xv = bf2f((unsigned short)((wvp[h] >> (16 * kb)) & 0xFFFF));
            float y = bn_sc[cc] * xv + bn_sh[cc];
            y = (y > 0.f) ? y : (__expf(y) - 1.f);
            res |= ((unsigned int)f2bf(y)) << (16 * kb);
          }
          wvp[h] = res;
        }
        *(uint4*)&As[r * LDST + s * 8] = va;
      }
      uint4 vb = *(const uint4*)(Bt + (size_t)(n0 + r) * Kp + kk + s * 8);
      *(uint4*)&Bs[r * LDST + s * 8] = vb;
    }
    __syncthreads();
    bf16x8 af[4], bfr[4];
    #pragma unroll
    for (int i = 0; i < 4; ++i)
      af[i] = *(const bf16x8*)&As[(wm + i * 16 + l16) * LDST + quad * 8];
    #pragma unroll
    for (int j = 0; j < 4; ++j)
      bfr[j] = *(const bf16x8*)&Bs[(wn + j * 16 + l16) * LDST + quad * 8];
    #pragma unroll
    for (int i = 0; i < 4; ++i)
      #pragma unroll
      for (int j = 0; j < 4; ++j)
        acc[i][j] = __builtin_amdgcn_mfma_f32_16x16x32_bf16(af[i], bfr[j], acc[i][j], 0, 0, 0);
    __syncthreads();
  }

  if (MODE == 0){
    float uu[4], vv[4], ww[4];
    #pragma unroll
    for (int j = 0; j < 4; ++j){
      int col = n0 + wn + j * 16 + l16;
      uu[j] = uvw[col]; vv[j] = uvw[256 + col]; ww[j] = uvw[512 + col];
    }
    #pragma unroll
    for (int i = 0; i < 4; ++i){
      #pragma unroll
      for (int r = 0; r < 4; ++r){
        int row = row0 + wm + i * 16 + quad * 4 + r;
        if (row < M){
          int b = batch[row];
          int st = starts[b];
          int cc = starts[b + 1] - st;
          int g2 = (int)ceilf(sqrtf((float)cc));
          int dd = g2 - 1; if (dd < 1) dd = 1;
          float idn = 1.0f / (float)dd;
          int ii = row - st;
          int irow = ii / g2;
          int icol = ii - irow * g2;
          float rn = (float)irow * idn, cn = (float)icol * idn;
          #pragma unroll
          for (int j = 0; j < 4; ++j)
            acc[i][j][r] += rn * uu[j] + cn * vv[j] + ww[j];
        }
      }
    }
  }

  // C store: C/D layout col=lane&15, row=quad*4+reg
  #pragma unroll
  for (int i = 0; i < 4; ++i){
    int rbase = row0 + wm + i * 16 + quad * 4;
    #pragma unroll
    for (int j = 0; j < 4; ++j){
      int col = n0 + wn + j * 16 + l16;
      #pragma unroll
      for (int r = 0; r < 4; ++r){
        int row = rbase + r;
        if (row < M) C[(size_t)row * 256 + col] = f2bf(acc[i][j][r]);
      }
    }
  }
  // fused alphas: this wave's columns n0+wn..+63 == head hda
  int hda = (n0 + wn) >> 6;
  float asw[4], adw[4];
  #pragma unroll
  for (int j = 0; j < 4; ++j){
    int c = n0 + wn + j * 16 + l16;
    asw[j] = a_src[c];
    adw[j] = a_dst[c];
  }
  #pragma unroll
  for (int i = 0; i < 4; ++i){
    #pragma unroll
    for (int r = 0; r < 4; ++r){
      int row = row0 + wm + i * 16 + quad * 4 + r;
      float ps = acc[i][0][r] * asw[0] + acc[i][1][r] * asw[1]
               + acc[i][2][r] * asw[2] + acc[i][3][r] * asw[3];
      float pd = acc[i][0][r] * adw[0] + acc[i][1][r] * adw[1]
               + acc[i][2][r] * adw[2] + acc[i][3][r] * adw[3];
      ps += __shfl_xor(ps, 1); ps += __shfl_xor(ps, 2);
      ps += __shfl_xor(ps, 4); ps += __shfl_xor(ps, 8);
      pd += __shfl_xor(pd, 1); pd += __shfl_xor(pd, 2);
      pd += __shfl_xor(pd, 4); pd += __shfl_xor(pd, 8);
      if (l16 == 0 && row < M){
        alpS[row * 4 + hda] = ps;
        alpD[row * 4 + hda] = pd;
      }
    }
  }
}

// ---- GAT aggregation: PERSISTENT grid-stride (R9 core per node) -------------
__global__ __launch_bounds__(256) void k_aggregate(const unsigned short* __restrict__ hlin,
                                                   const float* __restrict__ alpS,
                                                   const float* __restrict__ alpD,
                                                   const int* __restrict__ cnt,
                                                   const int* __restrict__ csr_src,
                                                   const float* __restrict__ bias,
                                                   unsigned short* __restrict__ outb,
                                                   float* __restrict__ bnP,
                                                   int N, int ngroups){
  __shared__ float rs[4][256];
  __shared__ float rq[4][256];
  int wv = threadIdx.x >> 6;
  int lane = threadIdx.x & 63;
  int hd = lane >> 4;          // channel-domain head
  int hd2 = lane & 3;          // score-domain head
  int eloc = lane >> 2;        // score-domain edge slot 0..15
  const unsigned short* hbase = hlin + (size_t)lane * 4;
  float4 bv = *(const float4*)(bias + lane * 4);

  float s0 = 0.f, s1 = 0.f, s2 = 0.f, s3 = 0.f;
  float q0 = 0.f, q1 = 0.f, q2 = 0.f, q3 = 0.f;

  for (int grp = blockIdx.x; grp < ngroups; grp += gridDim.x){
    int n = grp * 4 + wv;
    if (n < N){                      // wave-uniform
      int beg = n << 6;              // DEG_CAP = 64 fixed stride
      int deg = cnt[n];
      int total = deg + 1;           // + implicit self-loop
      float ad2 = alpD[n * 4 + hd2];
      float lsum = 0.f;
      float a0 = 0.f, a1 = 0.f, a2 = 0.f, a3 = 0.f;

      int full = total & ~15;
      for (int base = 0; base < full; base += 16){
        int e = base + eloc;                    // always < total
        int s = (e < deg) ? csr_src[beg + e] : n;
        float xv = alpS[s * 4 + hd2] + ad2;
        float sc = (xv >= 0.f) ? xv : 0.2f * xv;
        float p = __expf(sc);
        lsum += p;
        uint2 v[16];
        #pragma unroll
        for (int j2 = 0; j2 < 16; ++j2){
          int sj = __shfl(s, j2 << 2);
          v[j2] = *(const uint2*)(hbase + (size_t)sj * 256);
        }
        #pragma unroll
        for (int j2 = 0; j2 < 16; ++j2){
          float pj = __shfl(p, (j2 << 2) | hd);
          a0 += pj * __uint_as_float(v[j2].x << 16);
          a1 += pj * __uint_as_float(v[j2].x & 0xFFFF0000u);
          a2 += pj * __uint_as_float(v[j2].y << 16);
          a3 += pj * __uint_as_float(v[j2].y & 0xFFFF0000u);
        }
      }
      int rem = total - full;                   // 0..15
      if (rem){
        int e = full + eloc;
        int s = n;
        float p = 0.f;
        if (eloc < rem){
          if (e < deg) s = csr_src[beg + e];
          float xv = alpS[s * 4 + hd2] + ad2;
          float sc = (xv >= 0.f) ? xv : 0.2f * xv;
          p = __expf(sc);
        }
        lsum += p;
        #pragma unroll
        for (int g = 0; g < 4; ++g){
          if (g * 4 < rem){                     // wave-uniform branch
            uint2 v[4];
            #pragma unroll
            for (int q = 0; q < 4; ++q){
              int j2 = g * 4 + q;
              int sj = __shfl(s, j2 << 2);
              v[q] = *(const uint2*)(hbase + (size_t)sj * 256);
            }
            #pragma unroll
            for (int q = 0; q < 4; ++q){
              int j2 = g * 4 + q;
              float pj = __shfl(p, (j2 << 2) | hd);
              a0 += pj * __uint_as_float(v[q].x << 16);
              a1 += pj * __uint_as_float(v[q].x & 0xFFFF0000u);
              a2 += pj * __uint_as_float(v[q].y << 16);
              a3 += pj * __uint_as_float(v[q].y & 0xFFFF0000u);
            }
          }
        }
      }
      lsum += __shfl_xor(lsum, 4);
      lsum += __shfl_xor(lsum, 8);
      lsum += __shfl_xor(lsum, 16);
      lsum += __shfl_xor(lsum, 32);
      float lh = __shfl(lsum, hd);
      float inv = 1.0f / lh;
      ushort4 o;
      o.x = f2bf(a0 * inv + bv.x);
      o.y = f2bf(a1 * inv + bv.y);
      o.z = f2bf(a2 * inv + bv.z);
      o.w = f2bf(a3 * inv + bv.w);
      *(ushort4*)(outb + (size_t)n * 256 + lane * 4) = o;
      float f0 = bf2f(o.x), f1 = bf2f(o.y), f2 = bf2f(o.z), f3 = bf2f(o.w);
      s0 += f0; s1 += f1; s2 += f2; s3 += f3;
      q0 += f0 * f0; q1 += f1 * f1; q2 += f2 * f2; q3 += f3 * f3;
    }
  }

  // once-per-block sliced BN-stats epilogue
  int c0 = lane * 4;
  rs[wv][c0 + 0] = s0; rs[wv][c0 + 1] = s1;
  rs[wv][c0 + 2] = s2; rs[wv][c0 + 3] = s3;
  rq[wv][c0 + 0] = q0; rq[wv][c0 + 1] = q1;
  rq[wv][c0 + 2] = q2; rq[wv][c0 + 3] = q3;
  __syncthreads();
  int t = threadIdx.x;
  float s = rs[0][t] + rs[1][t] + rs[2][t] + rs[3][t];
  float q = rq[0][t] + rq[1][t] + rq[2][t] + rq[3][t];
  float* bp = bnP + (size_t)(blockIdx.x & (NSLICE - 1)) * 512;
  atomicAdd(&bp[t], s);
  atomicAdd(&bp[256 + t], q);
}

// ---- tail: BN+ELU + mean-pool + final FC, one block per graph ---------------
__global__ __launch_bounds__(1024) void k_tail(
    const unsigned short* __restrict__ in, const float* __restrict__ bnP,
    const float* __restrict__ gamma, const float* __restrict__ beta,
    const int* __restrict__ starts, const float* __restrict__ W_fc,
    const float* __restrict__ b_fc, float* __restrict__ out, float invN){
  __shared__ float pm[4][256];
  __shared__ float scs[256], shs[256];
  int t = threadIdx.x;
  int c = t & 255;        // channel
  int seg = t >> 8;       // row segment 0..3
  if (t < 256){
    float s = 0.f, q = 0.f;
    #pragma unroll
    for (int j = 0; j < NSLICE; ++j){
      s += bnP[j * 512 + t];
      q += bnP[j * 512 + 256 + t];
    }
    float mean = s * invN;
    float var = q * invN - mean * mean;
    float inv = rsqrtf(var + 1e-5f);
    float g = gamma[t];
    scs[t] = g * inv;
    shs[t] = beta[t] - mean * g * inv;
  }
  __syncthreads();
  int b = blockIdx.x;
  int r0 = starts[b], r1 = starts[b + 1];
  float scl = scs[c], shf = shs[c];
  float acc = 0.f;
  #pragma unroll 4
  for (int r = r0 + seg; r < r1; r += 4){
    float y = scl * bf2f(in[(size_t)r * 256 + c]) + shf;
    y = (y > 0.f) ? y : (__expf(y) - 1.f);
    acc += y;
  }
  pm[seg][c] = acc;
  __syncthreads();
  if (t < 256){
    int cnt = r1 - r0;
    float ic = (cnt > 0) ? 1.0f / (float)cnt : 0.f;
    pm[0][t] = (pm[0][t] + pm[1][t] + pm[2][t] + pm[3][t]) * ic;
  }
  __syncthreads();
  if (t < 128){
    float a = b_fc[t];
    #pragma unroll 4
    for (int cc = 0; cc < 256; ++cc) a += pm[0][cc] * W_fc[cc * 128 + t];
    out[b * 128 + t] = a;
  }
}

extern "C" void kernel_launch(void* const* d_in, const int* in_sizes, int n_in,
                              void* d_out, int out_size, void* d_ws, size_t ws_size,
                              hipStream_t stream){
  const float* x      = (const float*)d_in[0];
  const int*   eidx   = (const int*)  d_in[1];
  const int*   batch  = (const int*)  d_in[2];
  const float* W_pos  = (const float*)d_in[3];
  const float* b_pos  = (const float*)d_in[4];
  const float* W1     = (const float*)d_in[5];
  const float* a_src1 = (const float*)d_in[6];
  const float* a_dst1 = (const float*)d_in[7];
  const float* b1     = (const float*)d_in[8];
  const float* gamma1 = (const float*)d_in[9];
  const float* beta1  = (const float*)d_in[10];
  const float* W2     = (const float*)d_in[11];
  const float* a_src2 = (const float*)d_in[12];
  const float* a_dst2 = (const float*)d_in[13];
  const float* b2     = (const float*)d_in[14];
  const float* gamma2 = (const float*)d_in[15];
  const float* beta2  = (const float*)d_in[16];
  const float* W_fc   = (const float*)d_in[17];
  const float* b_fc   = (const float*)d_in[18];
  float* out = (float*)d_out;

  const int N = in_sizes[0] / 128;
  const int E = in_sizes[1] / 2;
  const int* esrc = eidx;
  const int* edst = eidx + E;

  char* w = (char*)d_ws;
  size_t off = 0;
  auto alloc = [&](size_t bytes) -> void* {
    void* p = w + off;
    off = (off + bytes + 255) & ~(size_t)255;
    return p;
  };
  unsigned short* X1b  = (unsigned short*)alloc((size_t)N * 256 * 2);  // GEMM out
  unsigned short* A1b  = (unsigned short*)alloc((size_t)N * 256 * 2);  // aggregate out
  float* alpS    = (float*)alloc((size_t)N * 4 * 4);
  float* alpD    = (float*)alloc((size_t)N * 4 * 4);
  int*   starts  = (int*)  alloc(65 * 4);
  int*   cnt     = (int*)  alloc((size_t)N * 4);
  int*   csr_src = (int*)  alloc((size_t)N * DEG_CAP * 4);
  float* bnP     = (float*)alloc((size_t)2 * NSLICE * 512 * 4);  // layer1 | layer2
  unsigned short* W1t = (unsigned short*)alloc(256 * 128 * 2);
  unsigned short* W2t = (unsigned short*)alloc(256 * 256 * 2);
  float* uvw = (float*)alloc(3 * 256 * 4);
  float* bnP1 = bnP, *bnP2 = bnP + NSLICE * 512;

  hipMemsetAsync(cnt, 0, (size_t)N * 4, stream);

  const int nfb = (E + 255) / 256;                  // front blocks
  const int ngroups = (N + 3) / 4;                  // 4-node groups

  // merged init: front + weight packs + uvw (all independent)
  k_init<<<nfb + 128 + 256 + 1, 256, 0, stream>>>(
      batch, starts, esrc, edst, cnt, csr_src, bnP,
      W_pos, b_pos, W1, W2, W1t, W2t, uvw, N, E, nfb);

  dim3 ggrid((N + 127) / 128, 2);
  const float invN = 1.0f / (float)N;

  // layer 1 (K=128, fp32-A in-staging convert, pos-correction epilogue)
  k_mfma_gemm<0><<<ggrid, 256, 0, stream>>>(nullptr, x, W1t, X1b, a_src1, a_dst1,
                                            alpS, alpD, N, 128, uvw, batch, starts,
                                            nullptr, nullptr, nullptr, 0.f);
  k_aggregate<<<AGG_BLOCKS, 256, 0, stream>>>(X1b, alpS, alpD, cnt, csr_src, b1,
                                              A1b, bnP1, N, ngroups);

  // layer 2 (BN1+ELU fused into A-staging; reads raw A1b, stats from bnP1)
  k_mfma_gemm<1><<<ggrid, 256, 0, stream>>>(A1b, nullptr, W2t, X1b, a_src2, a_dst2,
                                            alpS, alpD, N, 256, nullptr, nullptr, nullptr,
                                            bnP1, gamma1, beta1, invN);
  k_aggregate<<<AGG_BLOCKS, 256, 0, stream>>>(X1b, alpS, alpD, cnt, csr_src, b2,
                                              A1b, bnP2, N, ngroups);

  // tail: BN+ELU + mean-pool + FC (one block per graph)
  k_tail<<<64, 1024, 0, stream>>>(A1b, bnP2, gamma2, beta2, starts, W_fc, b_fc,
                                  out, invN);
}